// Round 6
// baseline (217.359 us; speedup 1.0000x reference)
//
#include <hip/hip_runtime.h>

// PointBasedTransform: hard voxelization with per-voxel cap & confidence ordering.
// N = 1572864 points, G=32 (NVOXEL=32768), MAX_PTS=16, MIN_PTS=15.
// Deterministic two-level counting sort; 6 launches:
// hist -> binprefix -> scatter -> voxconf(fused, +filt prefix) -> select(+256-scan) -> emit(NT)

#define NG 32
#define NVOXEL 32768
#define TILE 4096
#define VCAP 8192   // max points per coarse voxel bin (~3146 expected)
#define CCAP 8192   // max points per coarse conf bin (~6144 expected)

typedef float v4f __attribute__((ext_vector_type(4)));
typedef unsigned v2u __attribute__((ext_vector_type(2)));

__device__ __forceinline__ int conf_bucket(float c) {
  int b = (int)(c * 65536.0f);
  return b < 0 ? 0 : (b > 65535 ? 65535 : b);
}

// exclusive block scan over blockDim.x values (Hillis-Steele in LDS)
__device__ int block_scan_excl(int v, int* lds) {
  int t = threadIdx.x;
  lds[t] = v;
  __syncthreads();
  for (int off = 1; off < (int)blockDim.x; off <<= 1) {
    int x = (t >= off) ? lds[t - off] : 0;
    __syncthreads();
    lds[t] += x;
    __syncthreads();
  }
  int incl = lds[t];
  __syncthreads();
  return incl - v;
}

// per-tile: packed vid per point (ushort) + per-block 256-bin histograms (LDS only)
__global__ __launch_bounds__(256) void k_hist(int n, const float* __restrict__ pts,
                                              const float* __restrict__ conf,
                                              const float* __restrict__ center,
                                              unsigned short* __restrict__ code,
                                              int* __restrict__ blockHistV,
                                              int* __restrict__ blockHistC) {
  __shared__ int vh[256], ch[256];
  int t = threadIdx.x;
  vh[t] = 0; ch[t] = 0;
  __syncthreads();
  int base = blockIdx.x * TILE;
  float mx = center[0] - 0.64f, my = center[1] - 0.64f, mz = center[2] - 0.64f;
  for (int r = 0; r < TILE; r += 256) {
    int p = base + r + t;
    if (p < n) {
      float x = pts[3 * p], y = pts[3 * p + 1], z = pts[3 * p + 2];
      int ix = (int)floorf((x - mx) / 0.04f);
      int iy = (int)floorf((y - my) / 0.04f);
      int iz = (int)floorf((z - mz) / 0.04f);
      bool inb = (ix >= 0 && ix < NG && iy >= 0 && iy < NG && iz >= 0 && iz < NG);
      int vid = inb ? (ix * 1024 + iy * 32 + iz) : 0xFFFF;
      code[p] = (unsigned short)vid;
      if (inb) atomicAdd(&vh[vid >> 7], 1);
      atomicAdd(&ch[conf_bucket(conf[p]) >> 8], 1);
    }
  }
  __syncthreads();
  blockHistV[blockIdx.x * 256 + t] = vh[t];
  blockHistC[blockIdx.x * 256 + t] = ch[t];
}

// 512 blocks (bin 0..255 vox, 256..511 conf): prefix over scatter-blocks per bin
__global__ void k_binprefix(int nblk, const int* __restrict__ blockHistV,
                            const int* __restrict__ blockHistC, int* __restrict__ blockBaseV,
                            int* __restrict__ blockBaseC, int* __restrict__ totals) {
  __shared__ int lds[512];
  int t = threadIdx.x;
  int bin = blockIdx.x & 255;
  int isConf = blockIdx.x >> 8;
  const int* src = isConf ? blockHistC : blockHistV;
  int* dst = isConf ? blockBaseC : blockBaseV;
  int v = (t < nblk) ? src[t * 256 + bin] : 0;
  int ex = block_scan_excl(v, lds);
  if (t < nblk) dst[t * 256 + bin] = ex;
  if (t == nblk - 1) totals[blockIdx.x] = ex + v;
}

// per-tile single pass: place points into deterministic per-(block,bin) chunks.
__global__ __launch_bounds__(256) void k_scatter(int n, const unsigned short* __restrict__ code,
                                                 const float* __restrict__ conf,
                                                 const int* __restrict__ totals,
                                                 const int* __restrict__ blockBaseV,
                                                 const int* __restrict__ blockBaseC,
                                                 uint2* __restrict__ vidSeg,
                                                 float* __restrict__ confSeg) {
  __shared__ int curV[256], curC[256], lds[256];
  int t = threadIdx.x;
  int exV = block_scan_excl(totals[t], lds);
  int exC = block_scan_excl(totals[256 + t], lds);
  curV[t] = exV + blockBaseV[blockIdx.x * 256 + t];
  curC[t] = exC + blockBaseC[blockIdx.x * 256 + t];
  __syncthreads();
  int base = blockIdx.x * TILE;
  for (int r = 0; r < TILE; r += 256) {
    int p = base + r + t;
    if (p < n) {
      int vid = code[p];
      float c = conf[p];
      int cb = conf_bucket(c);
      if (vid != 0xFFFF) {
        int loc = atomicAdd(&curV[vid >> 7], 1);
        vidSeg[loc] = make_uint2(((unsigned)p << 7) | (unsigned)(vid & 127),
                                 __float_as_uint(c));
      }
      int loc2 = atomicAdd(&curC[cb >> 8], 1);
      confSeg[loc2] = c;
    }
  }
}

// fused: blocks 0..255 voxel-bin counting sort (+filtered prefix); 256..511 conf value sort
__global__ __launch_bounds__(256) void k_voxconf(int n, const uint2* __restrict__ vidSeg,
                                                 const float* __restrict__ confSeg,
                                                 const int* __restrict__ totals,
                                                 uint2* __restrict__ ptlist2,
                                                 int* __restrict__ counts0,
                                                 int* __restrict__ rawOff,
                                                 int* __restrict__ filtLocal,
                                                 int* __restrict__ filtBinTot,
                                                 float* __restrict__ confSorted) {
  __shared__ uint2 seg[VCAP];          // 64 KB, aliased by conf path as A/B
  __shared__ int cnt[257], off2[257], scan_t[256];
  __shared__ int s0_sh;
  int t = threadIdx.x;
  if (blockIdx.x < 256) {
    int b = blockIdx.x;
    int ex = block_scan_excl(totals[t], scan_t);
    if (t == b) s0_sh = ex;
    if (t < 128) cnt[t] = 0;
    __syncthreads();
    int s0 = s0_sh;
    int m = totals[b];
    if (m > VCAP) m = VCAP;
    for (int e = t; e < m; e += 256) {
      v2u pk2 = __builtin_nontemporal_load((const v2u*)&vidSeg[s0 + e]);
      uint2 pk = make_uint2(pk2.x, pk2.y);
      seg[e] = pk;
      atomicAdd(&cnt[pk.x & 127u], 1);
    }
    __syncthreads();
    int c = (t < 128) ? cnt[t] : 0;
    int ex2 = block_scan_excl(c, scan_t);
    int cf = (c > 15) ? c : 0;
    int exf = block_scan_excl(cf, scan_t);
    if (t < 128) {
      off2[t] = ex2;
      counts0[b * 128 + t] = c;
      rawOff[b * 128 + t] = s0 + ex2;
      filtLocal[b * 128 + t] = exf;
      cnt[t] = 0;  // reuse as cursor
    }
    if (t == 127) filtBinTot[b] = exf + cf;
    __syncthreads();
    for (int e = t; e < m; e += 256) {
      uint2 pk = seg[e];
      int v = (int)(pk.x & 127u);
      int loc = atomicAdd(&cnt[v], 1);
      ptlist2[s0 + off2[v] + loc] = make_uint2(pk.x >> 7, pk.y);
    }
  } else {
    int b = blockIdx.x - 256;
    float* A = (float*)seg;
    float* B = A + CCAP;
    int ex = block_scan_excl(totals[256 + t], scan_t);
    if (t == b) s0_sh = ex;
    cnt[t] = 0;
    __syncthreads();
    int s0 = s0_sh;
    int m = totals[256 + b];
    if (m > CCAP) m = CCAP;
    for (int e = t; e < m; e += 256) {
      float c = __builtin_nontemporal_load(&confSeg[s0 + e]);
      A[e] = c;
      atomicAdd(&cnt[conf_bucket(c) & 255], 1);
    }
    __syncthreads();
    int ex2 = block_scan_excl(cnt[t], scan_t);
    off2[t] = ex2;
    if (t == 0) off2[256] = m;
    cnt[t] = 0;  // reuse as cursor
    __syncthreads();
    for (int e = t; e < m; e += 256) {
      float c = A[e];
      int f = conf_bucket(c) & 255;
      int loc = atomicAdd(&cnt[f], 1);
      B[off2[f] + loc] = c;
    }
    __syncthreads();
    for (int e = t; e < m; e += 256) {
      int lo = 0, hi = 255;
      while (lo < hi) { int mid = (lo + hi + 1) >> 1; if (off2[mid] <= e) lo = mid; else hi = mid - 1; }
      int fend = off2[lo + 1];
      float v = B[e];
      int rank = 0;
      for (int q = off2[lo]; q < fend; q++) {
        float w = B[q];
        rank += (w > v || (w == v && q < e)) ? 1 : 0;
      }
      A[(m - fend) + rank] = v;  // descending within segment
    }
    __syncthreads();
    int dstBase = n - (s0 + m);
    for (int e = t; e < m; e += 256) confSorted[dstBase + e] = A[e];
  }
}

// one wave per voxel: 256-scan preamble derives filtOff; rank by (conf desc, idx asc)
__global__ __launch_bounds__(256) void k_select(const int* __restrict__ counts0,
                                                const int* __restrict__ rawOff,
                                                const int* __restrict__ filtLocal,
                                                const int* __restrict__ filtBinTot,
                                                const uint2* __restrict__ ptlist2,
                                                int* __restrict__ filtOff,
                                                int* __restrict__ filtTotal,
                                                int* __restrict__ rowPoint) {
  __shared__ float lc[4 * 256];
  __shared__ int li[4 * 256];
  __shared__ int scan_t[256], bb[256];
  int t = threadIdx.x;
  int fb = filtBinTot[t];
  int exb = block_scan_excl(fb, scan_t);
  bb[t] = exb;
  if (blockIdx.x == 0 && t == 255) filtTotal[0] = exb + fb;
  __syncthreads();
  int wave = threadIdx.x >> 6, lane = threadIdx.x & 63;
  int v = blockIdx.x * 4 + wave;
  int m = counts0[v];
  bool active = (m > 15);
  int base = rawOff[v];
  int out0 = bb[v >> 7] + filtLocal[v];
  if (lane == 0) filtOff[v] = out0;
  int staged = m < 256 ? m : 256;
  float* LC = &lc[wave * 256];
  int* LI = &li[wave * 256];
  if (active) {
    for (int e = lane; e < staged; e += 64) {
      uint2 pk = ptlist2[base + e];
      LI[e] = (int)pk.x;
      LC[e] = __uint_as_float(pk.y);
    }
  }
  __syncthreads();
  if (active) {
    for (int e = lane; e < m; e += 64) {
      int pe; float ce;
      if (e < staged) { pe = LI[e]; ce = LC[e]; }
      else { uint2 pk = ptlist2[base + e]; pe = (int)pk.x; ce = __uint_as_float(pk.y); }
      int rank = 0;
      for (int q = 0; q < m; q++) {
        float cq; int pq;
        if (q < staged) { cq = LC[q]; pq = LI[q]; }
        else { uint2 pk = ptlist2[base + q]; pq = (int)pk.x; cq = __uint_as_float(pk.y); }
        rank += (cq > ce || (cq == ce && pq < pe)) ? 1 : 0;
      }
      rowPoint[out0 + rank] = (rank < 16) ? pe : -1;
    }
  }
}

// fused emit with NT stores + NT loads on single-use gathers:
// desc(6n float4) | pts(3n) | conf(n) | dconf(n) | img(n) | table | occ | occgrid
__global__ __launch_bounds__(256) void k_emit(
    int n, const int* __restrict__ rowPoint, const int* __restrict__ filtTotal,
    const float* __restrict__ pts, const float* __restrict__ confSorted,
    const float* __restrict__ dconf, const int* __restrict__ imgid,
    const v4f* __restrict__ desc, const float* __restrict__ center,
    const int* __restrict__ counts0, const int* __restrict__ filtOff,
    const int* __restrict__ occ_in, float* __restrict__ pts_out,
    float* __restrict__ conf_out, v4f* __restrict__ desc_out,
    float* __restrict__ dconf_out, float* __restrict__ table_out,
    float* __restrict__ occupied_out, float* __restrict__ img_out,
    float* __restrict__ occgrid_out) {
  int j = blockIdx.x * blockDim.x + threadIdx.x;
  int T = filtTotal[0];
  if (j < 6 * n) {
    int i = j / 6, c = j - 6 * i;
    int p = (i < T) ? rowPoint[i] : -1;
    v4f val = {0.f, 0.f, 0.f, 0.f};
    if (p >= 0) val = __builtin_nontemporal_load(&desc[p * 6 + c]);
    __builtin_nontemporal_store(val, &desc_out[j]);
    return;
  }
  int j2 = j - 6 * n;
  if (j2 < 3 * n) {
    int i = j2 / 3, c = j2 - 3 * i;
    int p = (i < T) ? rowPoint[i] : -1;
    float o = 0.0f;
    if (p >= 0) {
      float mc = center[c] - 0.64f;
      float x = pts[3 * p + c];
      float fx = floorf((x - mc) / 0.04f);
      o = (x - mc - fx * 0.04f - 0.02f) / 0.02f;
    }
    __builtin_nontemporal_store(o, &pts_out[j2]);
    return;
  }
  j2 -= 3 * n;
  if (j2 < n) {
    int p = (j2 < T) ? rowPoint[j2] : -1;
    float o = (p >= 0) ? confSorted[p] : 0.0f;  // ref quirk: rank-indexed conf
    __builtin_nontemporal_store(o, &conf_out[j2]);
    return;
  }
  j2 -= n;
  if (j2 < n) {
    int p = (j2 < T) ? rowPoint[j2] : -1;
    float o = (p >= 0) ? __builtin_nontemporal_load(&dconf[p]) : 0.0f;
    __builtin_nontemporal_store(o, &dconf_out[j2]);
    return;
  }
  j2 -= n;
  if (j2 < n) {
    int p = (j2 < T) ? rowPoint[j2] : -1;
    float o = (p >= 0) ? (float)__builtin_nontemporal_load(&imgid[p]) : -1.0f;
    __builtin_nontemporal_store(o, &img_out[j2]);
    return;
  }
  j2 -= n;
  if (j2 < NVOXEL * 16) {
    int v = j2 >> 4, c = j2 & 15;
    bool occ = counts0[v] > 15;
    float o = occ ? (float)(filtOff[v] + c) : -1.0f;
    __builtin_nontemporal_store(o, &table_out[j2]);
    return;
  }
  j2 -= NVOXEL * 16;
  if (j2 < NVOXEL) {
    float o = (counts0[j2] > 15) ? 1.0f : 0.0f;
    __builtin_nontemporal_store(o, &occupied_out[j2]);
    return;
  }
  j2 -= NVOXEL;
  if (j2 < NVOXEL) {
    float o = (float)occ_in[j2];
    __builtin_nontemporal_store(o, &occgrid_out[j2]);
  }
}

extern "C" void kernel_launch(void* const* d_in, const int* in_sizes, int n_in,
                              void* d_out, int out_size, void* d_ws, size_t ws_size,
                              hipStream_t stream) {
  const int N = in_sizes[0] / 3;
  const float* pts   = (const float*)d_in[0];
  const float* conf  = (const float*)d_in[1];
  const float* desc  = (const float*)d_in[2];
  const float* dconf = (const float*)d_in[3];
  const int* imgid   = (const int*)d_in[4];
  const float* center = (const float*)d_in[5];
  const int* occg    = (const int*)d_in[6];

  float* out = (float*)d_out;
  float* pts_out      = out;
  float* conf_out     = out + (size_t)3 * N;
  float* desc_out     = out + (size_t)4 * N;
  float* dconf_out    = out + (size_t)28 * N;
  float* table_out    = out + (size_t)29 * N;
  float* occupied_out = table_out + (size_t)NVOXEL * 16;
  float* img_out      = occupied_out + NVOXEL;
  float* occgrid_out  = img_out + N;

  const int nTiles = (N + TILE - 1) / TILE;

  char* w = (char*)d_ws;
  uint2* vidSeg    = (uint2*)w;    w += (size_t)N * 8;
  uint2* ptlist2   = (uint2*)w;    w += (size_t)N * 8;
  float* confSeg   = (float*)w;    w += (size_t)N * 4;
  float* confSort  = (float*)w;    w += (size_t)N * 4;
  int* rowPoint    = (int*)w;      w += (size_t)N * 4;
  unsigned short* code = (unsigned short*)w; w += (size_t)N * 2;
  w = (char*)(((size_t)w + 255) & ~(size_t)255);
  int* counts0     = (int*)w;      w += (size_t)NVOXEL * 4;
  int* rawOff      = (int*)w;      w += (size_t)NVOXEL * 4;
  int* filtOff     = (int*)w;      w += (size_t)NVOXEL * 4;
  int* filtLocal   = (int*)w;      w += (size_t)NVOXEL * 4;
  int* blockHistV  = (int*)w;      w += (size_t)nTiles * 256 * 4;
  int* blockHistC  = (int*)w;      w += (size_t)nTiles * 256 * 4;
  int* blockBaseV  = (int*)w;      w += (size_t)nTiles * 256 * 4;
  int* blockBaseC  = (int*)w;      w += (size_t)nTiles * 256 * 4;
  int* totals      = (int*)w;      w += 512 * 4;
  int* filtBinTot  = (int*)w;      w += 256 * 4;
  int* filtTotal   = (int*)w;      w += 4;

  const int B = 256;

  k_hist<<<nTiles, B, 0, stream>>>(N, pts, conf, center, code, blockHistV, blockHistC);
  k_binprefix<<<512, 512, 0, stream>>>(nTiles, blockHistV, blockHistC, blockBaseV, blockBaseC,
                                       totals);
  k_scatter<<<nTiles, B, 0, stream>>>(N, code, conf, totals, blockBaseV, blockBaseC,
                                      vidSeg, confSeg);
  k_voxconf<<<512, B, 0, stream>>>(N, vidSeg, confSeg, totals, ptlist2, counts0, rawOff,
                                   filtLocal, filtBinTot, confSort);
  k_select<<<NVOXEL / 4, 256, 0, stream>>>(counts0, rawOff, filtLocal, filtBinTot, ptlist2,
                                           filtOff, filtTotal, rowPoint);

  const long long totalJ = 12LL * N + (long long)NVOXEL * 16 + 2LL * NVOXEL;
  const int gE = (int)((totalJ + B - 1) / B);
  k_emit<<<gE, B, 0, stream>>>(N, rowPoint, filtTotal, pts, confSort, dconf, imgid,
                               (const v4f*)desc, center, counts0, filtOff, occg, pts_out,
                               conf_out, (v4f*)desc_out, dconf_out, table_out, occupied_out,
                               img_out, occgrid_out);
}

// Round 7
// 202.334 us; speedup vs baseline: 1.0743x; 1.0743x over previous
//
#include <hip/hip_runtime.h>

// PointBasedTransform: hard voxelization with per-voxel cap & confidence ordering.
// N = 1572864 points, G=32 (NVOXEL=32768), MAX_PTS=16, MIN_PTS=15.
// Deterministic two-level counting sort; 6 launches:
// hist -> binprefix -> scatter -> voxconf(fused, +filt prefix) -> select(+256-scan) -> emit
// NT stores on outputs only; plain loads everywhere (NT loads on L2-hot scratch regressed R6).

#define NG 32
#define NVOXEL 32768
#define TILE 4096
#define VCAP 8192   // max points per coarse voxel bin (~3146 expected)
#define CCAP 8192   // max points per coarse conf bin (~6144 expected)

typedef float v4f __attribute__((ext_vector_type(4)));

__device__ __forceinline__ int conf_bucket(float c) {
  int b = (int)(c * 65536.0f);
  return b < 0 ? 0 : (b > 65535 ? 65535 : b);
}

// exclusive block scan over blockDim.x values (Hillis-Steele in LDS)
__device__ int block_scan_excl(int v, int* lds) {
  int t = threadIdx.x;
  lds[t] = v;
  __syncthreads();
  for (int off = 1; off < (int)blockDim.x; off <<= 1) {
    int x = (t >= off) ? lds[t - off] : 0;
    __syncthreads();
    lds[t] += x;
    __syncthreads();
  }
  int incl = lds[t];
  __syncthreads();
  return incl - v;
}

// per-tile: packed vid per point (ushort) + per-block 256-bin histograms (LDS only)
__global__ __launch_bounds__(256) void k_hist(int n, const float* __restrict__ pts,
                                              const float* __restrict__ conf,
                                              const float* __restrict__ center,
                                              unsigned short* __restrict__ code,
                                              int* __restrict__ blockHistV,
                                              int* __restrict__ blockHistC) {
  __shared__ int vh[256], ch[256];
  int t = threadIdx.x;
  vh[t] = 0; ch[t] = 0;
  __syncthreads();
  int base = blockIdx.x * TILE;
  float mx = center[0] - 0.64f, my = center[1] - 0.64f, mz = center[2] - 0.64f;
  for (int r = 0; r < TILE; r += 256) {
    int p = base + r + t;
    if (p < n) {
      float x = pts[3 * p], y = pts[3 * p + 1], z = pts[3 * p + 2];
      int ix = (int)floorf((x - mx) / 0.04f);
      int iy = (int)floorf((y - my) / 0.04f);
      int iz = (int)floorf((z - mz) / 0.04f);
      bool inb = (ix >= 0 && ix < NG && iy >= 0 && iy < NG && iz >= 0 && iz < NG);
      int vid = inb ? (ix * 1024 + iy * 32 + iz) : 0xFFFF;
      code[p] = (unsigned short)vid;
      if (inb) atomicAdd(&vh[vid >> 7], 1);
      atomicAdd(&ch[conf_bucket(conf[p]) >> 8], 1);
    }
  }
  __syncthreads();
  blockHistV[blockIdx.x * 256 + t] = vh[t];
  blockHistC[blockIdx.x * 256 + t] = ch[t];
}

// 512 blocks (bin 0..255 vox, 256..511 conf): prefix over scatter-blocks per bin
__global__ void k_binprefix(int nblk, const int* __restrict__ blockHistV,
                            const int* __restrict__ blockHistC, int* __restrict__ blockBaseV,
                            int* __restrict__ blockBaseC, int* __restrict__ totals) {
  __shared__ int lds[512];
  int t = threadIdx.x;
  int bin = blockIdx.x & 255;
  int isConf = blockIdx.x >> 8;
  const int* src = isConf ? blockHistC : blockHistV;
  int* dst = isConf ? blockBaseC : blockBaseV;
  int v = (t < nblk) ? src[t * 256 + bin] : 0;
  int ex = block_scan_excl(v, lds);
  if (t < nblk) dst[t * 256 + bin] = ex;
  if (t == nblk - 1) totals[blockIdx.x] = ex + v;
}

// per-tile single pass: place points into deterministic per-(block,bin) chunks.
__global__ __launch_bounds__(256) void k_scatter(int n, const unsigned short* __restrict__ code,
                                                 const float* __restrict__ conf,
                                                 const int* __restrict__ totals,
                                                 const int* __restrict__ blockBaseV,
                                                 const int* __restrict__ blockBaseC,
                                                 uint2* __restrict__ vidSeg,
                                                 float* __restrict__ confSeg) {
  __shared__ int curV[256], curC[256], lds[256];
  int t = threadIdx.x;
  int exV = block_scan_excl(totals[t], lds);
  int exC = block_scan_excl(totals[256 + t], lds);
  curV[t] = exV + blockBaseV[blockIdx.x * 256 + t];
  curC[t] = exC + blockBaseC[blockIdx.x * 256 + t];
  __syncthreads();
  int base = blockIdx.x * TILE;
  for (int r = 0; r < TILE; r += 256) {
    int p = base + r + t;
    if (p < n) {
      int vid = code[p];
      float c = conf[p];
      int cb = conf_bucket(c);
      if (vid != 0xFFFF) {
        int loc = atomicAdd(&curV[vid >> 7], 1);
        vidSeg[loc] = make_uint2(((unsigned)p << 7) | (unsigned)(vid & 127),
                                 __float_as_uint(c));
      }
      int loc2 = atomicAdd(&curC[cb >> 8], 1);
      confSeg[loc2] = c;
    }
  }
}

// fused: blocks 0..255 voxel-bin counting sort (+filtered prefix); 256..511 conf value sort
__global__ __launch_bounds__(256) void k_voxconf(int n, const uint2* __restrict__ vidSeg,
                                                 const float* __restrict__ confSeg,
                                                 const int* __restrict__ totals,
                                                 uint2* __restrict__ ptlist2,
                                                 int* __restrict__ counts0,
                                                 int* __restrict__ rawOff,
                                                 int* __restrict__ filtLocal,
                                                 int* __restrict__ filtBinTot,
                                                 float* __restrict__ confSorted) {
  __shared__ uint2 seg[VCAP];          // 64 KB, aliased by conf path as A/B
  __shared__ int cnt[257], off2[257], scan_t[256];
  __shared__ int s0_sh;
  int t = threadIdx.x;
  if (blockIdx.x < 256) {
    int b = blockIdx.x;
    int ex = block_scan_excl(totals[t], scan_t);
    if (t == b) s0_sh = ex;
    if (t < 128) cnt[t] = 0;
    __syncthreads();
    int s0 = s0_sh;
    int m = totals[b];
    if (m > VCAP) m = VCAP;
    for (int e = t; e < m; e += 256) {
      uint2 pk = vidSeg[s0 + e];
      seg[e] = pk;
      atomicAdd(&cnt[pk.x & 127u], 1);
    }
    __syncthreads();
    int c = (t < 128) ? cnt[t] : 0;
    int ex2 = block_scan_excl(c, scan_t);
    int cf = (c > 15) ? c : 0;
    int exf = block_scan_excl(cf, scan_t);
    if (t < 128) {
      off2[t] = ex2;
      counts0[b * 128 + t] = c;
      rawOff[b * 128 + t] = s0 + ex2;
      filtLocal[b * 128 + t] = exf;
      cnt[t] = 0;  // reuse as cursor
    }
    if (t == 127) filtBinTot[b] = exf + cf;
    __syncthreads();
    for (int e = t; e < m; e += 256) {
      uint2 pk = seg[e];
      int v = (int)(pk.x & 127u);
      int loc = atomicAdd(&cnt[v], 1);
      ptlist2[s0 + off2[v] + loc] = make_uint2(pk.x >> 7, pk.y);
    }
  } else {
    int b = blockIdx.x - 256;
    float* A = (float*)seg;
    float* B = A + CCAP;
    int ex = block_scan_excl(totals[256 + t], scan_t);
    if (t == b) s0_sh = ex;
    cnt[t] = 0;
    __syncthreads();
    int s0 = s0_sh;
    int m = totals[256 + b];
    if (m > CCAP) m = CCAP;
    for (int e = t; e < m; e += 256) {
      float c = confSeg[s0 + e];
      A[e] = c;
      atomicAdd(&cnt[conf_bucket(c) & 255], 1);
    }
    __syncthreads();
    int ex2 = block_scan_excl(cnt[t], scan_t);
    off2[t] = ex2;
    if (t == 0) off2[256] = m;
    cnt[t] = 0;  // reuse as cursor
    __syncthreads();
    for (int e = t; e < m; e += 256) {
      float c = A[e];
      int f = conf_bucket(c) & 255;
      int loc = atomicAdd(&cnt[f], 1);
      B[off2[f] + loc] = c;
    }
    __syncthreads();
    for (int e = t; e < m; e += 256) {
      int lo = 0, hi = 255;
      while (lo < hi) { int mid = (lo + hi + 1) >> 1; if (off2[mid] <= e) lo = mid; else hi = mid - 1; }
      int fend = off2[lo + 1];
      float v = B[e];
      int rank = 0;
      for (int q = off2[lo]; q < fend; q++) {
        float w = B[q];
        rank += (w > v || (w == v && q < e)) ? 1 : 0;
      }
      A[(m - fend) + rank] = v;  // descending within segment
    }
    __syncthreads();
    int dstBase = n - (s0 + m);
    for (int e = t; e < m; e += 256) confSorted[dstBase + e] = A[e];
  }
}

// one wave per voxel: 256-scan preamble derives filtOff; rank by (conf desc, idx asc)
__global__ __launch_bounds__(256) void k_select(const int* __restrict__ counts0,
                                                const int* __restrict__ rawOff,
                                                const int* __restrict__ filtLocal,
                                                const int* __restrict__ filtBinTot,
                                                const uint2* __restrict__ ptlist2,
                                                int* __restrict__ filtOff,
                                                int* __restrict__ filtTotal,
                                                int* __restrict__ rowPoint) {
  __shared__ float lc[4 * 256];
  __shared__ int li[4 * 256];
  __shared__ int scan_t[256], bb[256];
  int t = threadIdx.x;
  int fb = filtBinTot[t];
  int exb = block_scan_excl(fb, scan_t);
  bb[t] = exb;
  if (blockIdx.x == 0 && t == 255) filtTotal[0] = exb + fb;
  __syncthreads();
  int wave = threadIdx.x >> 6, lane = threadIdx.x & 63;
  int v = blockIdx.x * 4 + wave;
  int m = counts0[v];
  bool active = (m > 15);
  int base = rawOff[v];
  int out0 = bb[v >> 7] + filtLocal[v];
  if (lane == 0) filtOff[v] = out0;
  int staged = m < 256 ? m : 256;
  float* LC = &lc[wave * 256];
  int* LI = &li[wave * 256];
  if (active) {
    for (int e = lane; e < staged; e += 64) {
      uint2 pk = ptlist2[base + e];
      LI[e] = (int)pk.x;
      LC[e] = __uint_as_float(pk.y);
    }
  }
  __syncthreads();
  if (active) {
    for (int e = lane; e < m; e += 64) {
      int pe; float ce;
      if (e < staged) { pe = LI[e]; ce = LC[e]; }
      else { uint2 pk = ptlist2[base + e]; pe = (int)pk.x; ce = __uint_as_float(pk.y); }
      int rank = 0;
      for (int q = 0; q < m; q++) {
        float cq; int pq;
        if (q < staged) { cq = LC[q]; pq = LI[q]; }
        else { uint2 pk = ptlist2[base + q]; pq = (int)pk.x; cq = __uint_as_float(pk.y); }
        rank += (cq > ce || (cq == ce && pq < pe)) ? 1 : 0;
      }
      rowPoint[out0 + rank] = (rank < 16) ? pe : -1;
    }
  }
}

// fused emit with NT stores (outputs never re-read); plain loads:
// desc(6n float4) | pts(3n) | conf(n) | dconf(n) | img(n) | table | occ | occgrid
__global__ __launch_bounds__(256) void k_emit(
    int n, const int* __restrict__ rowPoint, const int* __restrict__ filtTotal,
    const float* __restrict__ pts, const float* __restrict__ confSorted,
    const float* __restrict__ dconf, const int* __restrict__ imgid,
    const v4f* __restrict__ desc, const float* __restrict__ center,
    const int* __restrict__ counts0, const int* __restrict__ filtOff,
    const int* __restrict__ occ_in, float* __restrict__ pts_out,
    float* __restrict__ conf_out, v4f* __restrict__ desc_out,
    float* __restrict__ dconf_out, float* __restrict__ table_out,
    float* __restrict__ occupied_out, float* __restrict__ img_out,
    float* __restrict__ occgrid_out) {
  int j = blockIdx.x * blockDim.x + threadIdx.x;
  int T = filtTotal[0];
  if (j < 6 * n) {
    int i = j / 6, c = j - 6 * i;
    int p = (i < T) ? rowPoint[i] : -1;
    v4f val = {0.f, 0.f, 0.f, 0.f};
    if (p >= 0) val = desc[p * 6 + c];
    __builtin_nontemporal_store(val, &desc_out[j]);
    return;
  }
  int j2 = j - 6 * n;
  if (j2 < 3 * n) {
    int i = j2 / 3, c = j2 - 3 * i;
    int p = (i < T) ? rowPoint[i] : -1;
    float o = 0.0f;
    if (p >= 0) {
      float mc = center[c] - 0.64f;
      float x = pts[3 * p + c];
      float fx = floorf((x - mc) / 0.04f);
      o = (x - mc - fx * 0.04f - 0.02f) / 0.02f;
    }
    __builtin_nontemporal_store(o, &pts_out[j2]);
    return;
  }
  j2 -= 3 * n;
  if (j2 < n) {
    int p = (j2 < T) ? rowPoint[j2] : -1;
    float o = (p >= 0) ? confSorted[p] : 0.0f;  // ref quirk: rank-indexed conf
    __builtin_nontemporal_store(o, &conf_out[j2]);
    return;
  }
  j2 -= n;
  if (j2 < n) {
    int p = (j2 < T) ? rowPoint[j2] : -1;
    float o = (p >= 0) ? dconf[p] : 0.0f;
    __builtin_nontemporal_store(o, &dconf_out[j2]);
    return;
  }
  j2 -= n;
  if (j2 < n) {
    int p = (j2 < T) ? rowPoint[j2] : -1;
    float o = (p >= 0) ? (float)imgid[p] : -1.0f;
    __builtin_nontemporal_store(o, &img_out[j2]);
    return;
  }
  j2 -= n;
  if (j2 < NVOXEL * 16) {
    int v = j2 >> 4, c = j2 & 15;
    bool occ = counts0[v] > 15;
    float o = occ ? (float)(filtOff[v] + c) : -1.0f;
    __builtin_nontemporal_store(o, &table_out[j2]);
    return;
  }
  j2 -= NVOXEL * 16;
  if (j2 < NVOXEL) {
    float o = (counts0[j2] > 15) ? 1.0f : 0.0f;
    __builtin_nontemporal_store(o, &occupied_out[j2]);
    return;
  }
  j2 -= NVOXEL;
  if (j2 < NVOXEL) {
    float o = (float)occ_in[j2];
    __builtin_nontemporal_store(o, &occgrid_out[j2]);
  }
}

extern "C" void kernel_launch(void* const* d_in, const int* in_sizes, int n_in,
                              void* d_out, int out_size, void* d_ws, size_t ws_size,
                              hipStream_t stream) {
  const int N = in_sizes[0] / 3;
  const float* pts   = (const float*)d_in[0];
  const float* conf  = (const float*)d_in[1];
  const float* desc  = (const float*)d_in[2];
  const float* dconf = (const float*)d_in[3];
  const int* imgid   = (const int*)d_in[4];
  const float* center = (const float*)d_in[5];
  const int* occg    = (const int*)d_in[6];

  float* out = (float*)d_out;
  float* pts_out      = out;
  float* conf_out     = out + (size_t)3 * N;
  float* desc_out     = out + (size_t)4 * N;
  float* dconf_out    = out + (size_t)28 * N;
  float* table_out    = out + (size_t)29 * N;
  float* occupied_out = table_out + (size_t)NVOXEL * 16;
  float* img_out      = occupied_out + NVOXEL;
  float* occgrid_out  = img_out + N;

  const int nTiles = (N + TILE - 1) / TILE;

  char* w = (char*)d_ws;
  uint2* vidSeg    = (uint2*)w;    w += (size_t)N * 8;
  uint2* ptlist2   = (uint2*)w;    w += (size_t)N * 8;
  float* confSeg   = (float*)w;    w += (size_t)N * 4;
  float* confSort  = (float*)w;    w += (size_t)N * 4;
  int* rowPoint    = (int*)w;      w += (size_t)N * 4;
  unsigned short* code = (unsigned short*)w; w += (size_t)N * 2;
  w = (char*)(((size_t)w + 255) & ~(size_t)255);
  int* counts0     = (int*)w;      w += (size_t)NVOXEL * 4;
  int* rawOff      = (int*)w;      w += (size_t)NVOXEL * 4;
  int* filtOff     = (int*)w;      w += (size_t)NVOXEL * 4;
  int* filtLocal   = (int*)w;      w += (size_t)NVOXEL * 4;
  int* blockHistV  = (int*)w;      w += (size_t)nTiles * 256 * 4;
  int* blockHistC  = (int*)w;      w += (size_t)nTiles * 256 * 4;
  int* blockBaseV  = (int*)w;      w += (size_t)nTiles * 256 * 4;
  int* blockBaseC  = (int*)w;      w += (size_t)nTiles * 256 * 4;
  int* totals      = (int*)w;      w += 512 * 4;
  int* filtBinTot  = (int*)w;      w += 256 * 4;
  int* filtTotal   = (int*)w;      w += 4;

  const int B = 256;

  k_hist<<<nTiles, B, 0, stream>>>(N, pts, conf, center, code, blockHistV, blockHistC);
  k_binprefix<<<512, 512, 0, stream>>>(nTiles, blockHistV, blockHistC, blockBaseV, blockBaseC,
                                       totals);
  k_scatter<<<nTiles, B, 0, stream>>>(N, code, conf, totals, blockBaseV, blockBaseC,
                                      vidSeg, confSeg);
  k_voxconf<<<512, B, 0, stream>>>(N, vidSeg, confSeg, totals, ptlist2, counts0, rawOff,
                                   filtLocal, filtBinTot, confSort);
  k_select<<<NVOXEL / 4, 256, 0, stream>>>(counts0, rawOff, filtLocal, filtBinTot, ptlist2,
                                           filtOff, filtTotal, rowPoint);

  const long long totalJ = 12LL * N + (long long)NVOXEL * 16 + 2LL * NVOXEL;
  const int gE = (int)((totalJ + B - 1) / B);
  k_emit<<<gE, B, 0, stream>>>(N, rowPoint, filtTotal, pts, confSort, dconf, imgid,
                               (const v4f*)desc, center, counts0, filtOff, occg, pts_out,
                               conf_out, (v4f*)desc_out, dconf_out, table_out, occupied_out,
                               img_out, occgrid_out);
}